// Round 1
// baseline (568.929 us; speedup 1.0000x reference)
//
#include <hip/hip_runtime.h>

#define N_NODES 100000
#define DFEAT 64

// ---------------- CSR build ----------------

__global__ void k_init(int* deg, int* cursor, int n) {
    int i = blockIdx.x * 256 + threadIdx.x;
    if (i < n) { deg[i] = 0; cursor[i] = 0; }
}

__global__ void k_count(const int* __restrict__ dst, int* __restrict__ deg, int E) {
    int e = blockIdx.x * 256 + threadIdx.x;
    if (e < E) atomicAdd(&deg[dst[e]], 1);
}

__global__ void k_dinv(const int* __restrict__ deg, float* __restrict__ dinv, int n) {
    int i = blockIdx.x * 256 + threadIdx.x;
    if (i < n) dinv[i] = rsqrtf((float)(deg[i] + 1));  // +1 = self loop; always > 0
}

// exclusive scan of deg -> partial (per-block) + block sums
__global__ void k_scan_local(const int* __restrict__ deg, int* __restrict__ partial,
                             int* __restrict__ bsum, int n) {
    __shared__ int s[256];
    int tid = threadIdx.x;
    int i = blockIdx.x * 256 + tid;
    int v = (i < n) ? deg[i] : 0;
    s[tid] = v;
    __syncthreads();
    for (int off = 1; off < 256; off <<= 1) {
        int t = (tid >= off) ? s[tid - off] : 0;
        __syncthreads();
        s[tid] += t;
        __syncthreads();
    }
    if (i < n) partial[i] = s[tid] - v;  // exclusive within block
    if (tid == 255) bsum[blockIdx.x] = s[255];
}

// single block, 512 threads: exclusive scan of block sums (NB=391 <= 512)
__global__ void k_scan_bsum(const int* __restrict__ bsum, int* __restrict__ bsumex, int nb) {
    __shared__ int s[512];
    int tid = threadIdx.x;
    int v = (tid < nb) ? bsum[tid] : 0;
    s[tid] = v;
    __syncthreads();
    for (int off = 1; off < 512; off <<= 1) {
        int t = (tid >= off) ? s[tid - off] : 0;
        __syncthreads();
        s[tid] += t;
        __syncthreads();
    }
    bsumex[tid] = s[tid] - v;
}

__global__ void k_add_base(const int* __restrict__ partial, const int* __restrict__ bsumex,
                           int* __restrict__ offs, int n) {
    int i = blockIdx.x * 256 + threadIdx.x;
    if (i < n) offs[i] = partial[i] + bsumex[i >> 8];
}

__global__ void k_fill(const int* __restrict__ src, const int* __restrict__ dst,
                       const int* __restrict__ offs, int* __restrict__ cursor,
                       int* __restrict__ csr, int E) {
    int e = blockIdx.x * 256 + threadIdx.x;
    if (e < E) {
        int d = dst[e];
        int pos = offs[d] + atomicAdd(&cursor[d], 1);
        csr[pos] = src[e];
    }
}

// ---------------- per-layer kernels ----------------

// h = in @ W   (f32; no fp32 MFMA on CDNA4 -> vector ALU with LDS staging)
// block: 256 threads = 16 rows x (16 col-groups of 4 cols). grid: N/16 = 6250 (exact).
__global__ __launch_bounds__(256) void k_gemm(const float* __restrict__ in,
                                              const float* __restrict__ W,
                                              float* __restrict__ out) {
    __shared__ float Ws[64 * 64];        // 16 KB
    __shared__ float xs[16 * 65];        // pad 65: xs bank = (rl + k) % 32, conflict-free
    int tid = threadIdx.x;

    const float4* W4 = (const float4*)W;
    float4* Ws4 = (float4*)Ws;
#pragma unroll
    for (int j = 0; j < 4; j++) Ws4[tid + j * 256] = W4[tid + j * 256];

    {
        const float4* in4 = (const float4*)(in + (size_t)blockIdx.x * 16 * 64);
        float4 xv = in4[tid];
        int f = tid * 4;
        int r = f >> 6, c = f & 63;
        xs[r * 65 + c + 0] = xv.x;
        xs[r * 65 + c + 1] = xv.y;
        xs[r * 65 + c + 2] = xv.z;
        xs[r * 65 + c + 3] = xv.w;
    }
    __syncthreads();

    int cg = tid & 15, rl = tid >> 4;
    float4 acc = {0.f, 0.f, 0.f, 0.f};
#pragma unroll
    for (int k = 0; k < 64; k++) {
        float xv = xs[rl * 65 + k];
        float4 wv = ((const float4*)Ws)[k * 16 + cg];
        acc.x += xv * wv.x;
        acc.y += xv * wv.y;
        acc.z += xv * wv.z;
        acc.w += xv * wv.w;
    }
    float4* out4 = (float4*)(out + (size_t)blockIdx.x * 16 * 64);
    out4[rl * 16 + cg] = acc;
}

// out[i] = relu(b + dinv_i * (dinv_i*h[i] + sum_{j in N_in(i)} dinv_j*h[j]))
// one wave per node, lane = feature. coalesced 256B gather per edge, no atomics.
__global__ __launch_bounds__(256) void k_gather(const float* __restrict__ h,
                                                const float* __restrict__ dinv,
                                                const int* __restrict__ csr,
                                                const int* __restrict__ offs,
                                                const int* __restrict__ deg,
                                                const float* __restrict__ bias,
                                                float* __restrict__ out, int n) {
    int node = blockIdx.x * 4 + (threadIdx.x >> 6);
    int lane = threadIdx.x & 63;
    if (node >= n) return;
    float di = dinv[node];
    int start = offs[node];
    int cnt = deg[node];
    float acc = h[(size_t)node * 64 + lane] * di;  // self-loop term (x di again below)
    for (int e = 0; e < cnt; e++) {
        int j = csr[start + e];
        acc += h[(size_t)j * 64 + lane] * dinv[j];
    }
    out[(size_t)node * 64 + lane] = fmaxf(fmaf(acc, di, bias[lane]), 0.0f);
}

// ---------------- launch ----------------

extern "C" void kernel_launch(void* const* d_in, const int* in_sizes, int n_in,
                              void* d_out, int out_size, void* d_ws, size_t ws_size,
                              hipStream_t stream) {
    const float* x  = (const float*)d_in[0];
    const int*   ei = (const int*)d_in[1];   // int32 (jax x64 disabled -> int64 request folds to int32)
    const float* W0 = (const float*)d_in[2];
    const float* b0 = (const float*)d_in[3];
    const float* W1 = (const float*)d_in[4];
    const float* b1 = (const float*)d_in[5];
    const float* W2 = (const float*)d_in[6];
    const float* b2 = (const float*)d_in[7];
    float* out = (float*)d_out;

    const int N = N_NODES;
    const int E = in_sizes[1] / 2;
    const int* src = ei;
    const int* dst = ei + E;

    // workspace carve-up (~58 MB)
    char* p = (char*)d_ws;
    auto alloc = [&](size_t bytes) -> void* {
        void* r = (void*)p;
        p += (bytes + 511) & ~(size_t)511;
        return r;
    };
    int*   deg     = (int*)alloc((size_t)N * 4);
    int*   cursor  = (int*)alloc((size_t)N * 4);
    float* dinv    = (float*)alloc((size_t)N * 4);
    int*   partial = (int*)alloc((size_t)N * 4);
    int*   offs    = (int*)alloc((size_t)N * 4);
    int*   bsum    = (int*)alloc(512 * 4);
    int*   bsumex  = (int*)alloc(512 * 4);
    int*   csr     = (int*)alloc((size_t)E * 4);
    float* bufA    = (float*)alloc((size_t)N * DFEAT * 4);
    float* bufB    = (float*)alloc((size_t)N * DFEAT * 4);

    const int NB = (N + 255) / 256;      // 391
    const int EB = (E + 255) / 256;      // 3907
    const int GEMM_B = N / 16;           // 6250 (N divisible by 16)
    const int GATH_B = (N + 3) / 4;      // 25000

    // CSR build (amortized over 3 layers)
    k_init<<<NB, 256, 0, stream>>>(deg, cursor, N);
    k_count<<<EB, 256, 0, stream>>>(dst, deg, E);
    k_dinv<<<NB, 256, 0, stream>>>(deg, dinv, N);
    k_scan_local<<<NB, 256, 0, stream>>>(deg, partial, bsum, N);
    k_scan_bsum<<<1, 512, 0, stream>>>(bsum, bsumex, NB);
    k_add_base<<<NB, 256, 0, stream>>>(partial, bsumex, offs, N);
    k_fill<<<EB, 256, 0, stream>>>(src, dst, offs, cursor, csr, E);

    // layer 0: x -> A -> B
    k_gemm<<<GEMM_B, 256, 0, stream>>>(x, W0, bufA);
    k_gather<<<GATH_B, 256, 0, stream>>>(bufA, dinv, csr, offs, deg, b0, bufB, N);
    // layer 1: B -> A -> B
    k_gemm<<<GEMM_B, 256, 0, stream>>>(bufB, W1, bufA);
    k_gather<<<GATH_B, 256, 0, stream>>>(bufA, dinv, csr, offs, deg, b1, bufB, N);
    // layer 2: B -> A -> out
    k_gemm<<<GEMM_B, 256, 0, stream>>>(bufB, W2, bufA);
    k_gather<<<GATH_B, 256, 0, stream>>>(bufA, dinv, csr, offs, deg, b2, out, N);
}

// Round 2
// 412.772 us; speedup vs baseline: 1.3783x; 1.3783x over previous
//
#include <hip/hip_runtime.h>

#define N_NODES 100000
#define DFEAT 64

// ---------------- CSR build ----------------

__global__ void k_init(int* deg, int* cursor, int n) {
    int i = blockIdx.x * 256 + threadIdx.x;
    if (i < n) { deg[i] = 0; cursor[i] = 0; }
}

__global__ void k_count(const int* __restrict__ dst, int* __restrict__ deg, int E) {
    int e = blockIdx.x * 256 + threadIdx.x;
    if (e < E) atomicAdd(&deg[dst[e]], 1);
}

// exclusive scan of deg -> partial (per-block) + block sums; also dinv = rsqrt(deg+1)
__global__ void k_scan_local(const int* __restrict__ deg, int* __restrict__ partial,
                             int* __restrict__ bsum, float* __restrict__ dinv, int n) {
    __shared__ int s[256];
    int tid = threadIdx.x;
    int i = blockIdx.x * 256 + tid;
    int v = (i < n) ? deg[i] : 0;
    if (i < n) dinv[i] = rsqrtf((float)(v + 1));  // +1 = self loop; always > 0
    s[tid] = v;
    __syncthreads();
    for (int off = 1; off < 256; off <<= 1) {
        int t = (tid >= off) ? s[tid - off] : 0;
        __syncthreads();
        s[tid] += t;
        __syncthreads();
    }
    if (i < n) partial[i] = s[tid] - v;  // exclusive within block
    if (tid == 255) bsum[blockIdx.x] = s[255];
}

// single block, 512 threads: exclusive scan of block sums (NB=391 <= 512)
__global__ void k_scan_bsum(const int* __restrict__ bsum, int* __restrict__ bsumex, int nb) {
    __shared__ int s[512];
    int tid = threadIdx.x;
    int v = (tid < nb) ? bsum[tid] : 0;
    s[tid] = v;
    __syncthreads();
    for (int off = 1; off < 512; off <<= 1) {
        int t = (tid >= off) ? s[tid - off] : 0;
        __syncthreads();
        s[tid] += t;
        __syncthreads();
    }
    bsumex[tid] = s[tid] - v;
}

__global__ void k_add_base(const int* __restrict__ partial, const int* __restrict__ bsumex,
                           int* __restrict__ offs, int n) {
    int i = blockIdx.x * 256 + threadIdx.x;
    if (i < n) offs[i] = partial[i] + bsumex[i >> 8];
}

__global__ void k_fill(const int* __restrict__ src, const int* __restrict__ dst,
                       const int* __restrict__ offs, int* __restrict__ cursor,
                       int* __restrict__ csr, int E) {
    int e = blockIdx.x * 256 + threadIdx.x;
    if (e < E) {
        int d = dst[e];
        int pos = offs[d] + atomicAdd(&cursor[d], 1);
        csr[pos] = src[e];
    }
}

// ---------------- per-layer kernels ----------------

// h' = (in @ W) * dinv[row]   (f32; no fp32 MFMA on CDNA4 -> vector ALU, LDS staging)
// block: 256 threads = 16 rows x (16 col-groups of 4 cols). grid: N/16 = 6250 (exact).
__global__ __launch_bounds__(256) void k_gemm(const float* __restrict__ in,
                                              const float* __restrict__ W,
                                              const float* __restrict__ dinv,
                                              float* __restrict__ out) {
    __shared__ float Ws[64 * 64];        // 16 KB
    __shared__ float xs[16 * 65];        // pad 65: conflict-free
    int tid = threadIdx.x;

    const float4* W4 = (const float4*)W;
    float4* Ws4 = (float4*)Ws;
#pragma unroll
    for (int j = 0; j < 4; j++) Ws4[tid + j * 256] = W4[tid + j * 256];

    {
        const float4* in4 = (const float4*)(in + (size_t)blockIdx.x * 16 * 64);
        float4 xv = in4[tid];
        int f = tid * 4;
        int r = f >> 6, c = f & 63;
        xs[r * 65 + c + 0] = xv.x;
        xs[r * 65 + c + 1] = xv.y;
        xs[r * 65 + c + 2] = xv.z;
        xs[r * 65 + c + 3] = xv.w;
    }
    __syncthreads();

    int cg = tid & 15, rl = tid >> 4;
    float4 acc = {0.f, 0.f, 0.f, 0.f};
#pragma unroll
    for (int k = 0; k < 64; k++) {
        float xv = xs[rl * 65 + k];
        float4 wv = ((const float4*)Ws)[k * 16 + cg];
        acc.x += xv * wv.x;
        acc.y += xv * wv.y;
        acc.z += xv * wv.z;
        acc.w += xv * wv.w;
    }
    float d = dinv[blockIdx.x * 16 + rl];
    acc.x *= d; acc.y *= d; acc.z *= d; acc.w *= d;
    float4* out4 = (float4*)(out + (size_t)blockIdx.x * 16 * 64);
    out4[rl * 16 + cg] = acc;
}

// out[i] = relu(dinv_i * (h'[i] + sum_{j in N_in(i)} h'[j]) + b)   where h' is pre-scaled by dinv
// one wave per node, lane = feature. 4-way unrolled -> 4 gathers in flight, no atomics.
__global__ __launch_bounds__(256) void k_gather(const float* __restrict__ h,
                                                const float* __restrict__ dinv,
                                                const int* __restrict__ csr,
                                                const int* __restrict__ offs,
                                                const int* __restrict__ deg,
                                                const float* __restrict__ bias,
                                                float* __restrict__ out, int n) {
    int node = blockIdx.x * 4 + (threadIdx.x >> 6);
    int lane = threadIdx.x & 63;
    if (node >= n) return;
    int start = offs[node];
    int cnt = deg[node];
    const float* hl = h + lane;
    float acc0 = hl[(size_t)node * 64];   // self-loop term (h' already has dinv_node)
    float acc1 = 0.f, acc2 = 0.f, acc3 = 0.f;
    int e = 0;
    for (; e + 4 <= cnt; e += 4) {
        int j0 = csr[start + e + 0];
        int j1 = csr[start + e + 1];
        int j2 = csr[start + e + 2];
        int j3 = csr[start + e + 3];
        acc0 += hl[(size_t)j0 * 64];
        acc1 += hl[(size_t)j1 * 64];
        acc2 += hl[(size_t)j2 * 64];
        acc3 += hl[(size_t)j3 * 64];
    }
    for (; e < cnt; e++) {
        int j = csr[start + e];
        acc0 += hl[(size_t)j * 64];
    }
    float acc = (acc0 + acc1) + (acc2 + acc3);
    out[(size_t)node * 64 + lane] = fmaxf(fmaf(acc, dinv[node], bias[lane]), 0.0f);
}

// ---------------- launch ----------------

extern "C" void kernel_launch(void* const* d_in, const int* in_sizes, int n_in,
                              void* d_out, int out_size, void* d_ws, size_t ws_size,
                              hipStream_t stream) {
    const float* x  = (const float*)d_in[0];
    const int*   ei = (const int*)d_in[1];
    const float* W0 = (const float*)d_in[2];
    const float* b0 = (const float*)d_in[3];
    const float* W1 = (const float*)d_in[4];
    const float* b1 = (const float*)d_in[5];
    const float* W2 = (const float*)d_in[6];
    const float* b2 = (const float*)d_in[7];
    float* out = (float*)d_out;

    const int N = N_NODES;
    const int E = in_sizes[1] / 2;
    const int* src = ei;
    const int* dst = ei + E;

    // workspace carve-up (~58 MB)
    char* p = (char*)d_ws;
    auto alloc = [&](size_t bytes) -> void* {
        void* r = (void*)p;
        p += (bytes + 511) & ~(size_t)511;
        return r;
    };
    int*   deg     = (int*)alloc((size_t)N * 4);
    int*   cursor  = (int*)alloc((size_t)N * 4);
    float* dinv    = (float*)alloc((size_t)N * 4);
    int*   partial = (int*)alloc((size_t)N * 4);
    int*   offs    = (int*)alloc((size_t)N * 4);
    int*   bsum    = (int*)alloc(512 * 4);
    int*   bsumex  = (int*)alloc(512 * 4);
    int*   csr     = (int*)alloc((size_t)E * 4);
    float* bufA    = (float*)alloc((size_t)N * DFEAT * 4);
    float* bufB    = (float*)alloc((size_t)N * DFEAT * 4);

    const int NB = (N + 255) / 256;      // 391
    const int EB = (E + 255) / 256;      // 3907
    const int GEMM_B = N / 16;           // 6250
    const int GATH_B = (N + 3) / 4;      // 25000

    // CSR build (amortized over 3 layers)
    k_init<<<NB, 256, 0, stream>>>(deg, cursor, N);
    k_count<<<EB, 256, 0, stream>>>(dst, deg, E);
    k_scan_local<<<NB, 256, 0, stream>>>(deg, partial, bsum, dinv, N);
    k_scan_bsum<<<1, 512, 0, stream>>>(bsum, bsumex, NB);
    k_add_base<<<NB, 256, 0, stream>>>(partial, bsumex, offs, N);
    k_fill<<<EB, 256, 0, stream>>>(src, dst, offs, cursor, csr, E);

    // layer 0: x -> A -> B
    k_gemm<<<GEMM_B, 256, 0, stream>>>(x, W0, dinv, bufA);
    k_gather<<<GATH_B, 256, 0, stream>>>(bufA, dinv, csr, offs, deg, b0, bufB, N);
    // layer 1: B -> A -> B
    k_gemm<<<GEMM_B, 256, 0, stream>>>(bufB, W1, dinv, bufA);
    k_gather<<<GATH_B, 256, 0, stream>>>(bufA, dinv, csr, offs, deg, b1, bufB, N);
    // layer 2: B -> A -> out
    k_gemm<<<GEMM_B, 256, 0, stream>>>(bufB, W2, dinv, bufA);
    k_gather<<<GATH_B, 256, 0, stream>>>(bufA, dinv, csr, offs, deg, b2, out, N);
}

// Round 3
// 381.283 us; speedup vs baseline: 1.4921x; 1.0826x over previous
//
#include <hip/hip_runtime.h>

#define N_NODES 100000
#define DFEAT 64

// ---------------- CSR build ----------------

__global__ void k_init(int* deg, int n) {
    int i = blockIdx.x * 256 + threadIdx.x;
    if (i < n) deg[i] = 0;
}

__global__ void k_count(const int* __restrict__ dst, int* __restrict__ deg, int E) {
    int e = blockIdx.x * 256 + threadIdx.x;
    if (e < E) atomicAdd(&deg[dst[e]], 1);
}

// exclusive scan of deg -> partial (per-block) + block sums; also dinv = rsqrt(deg+1)
__global__ void k_scan_local(const int* __restrict__ deg, int* __restrict__ partial,
                             int* __restrict__ bsum, float* __restrict__ dinv, int n) {
    __shared__ int s[256];
    int tid = threadIdx.x;
    int i = blockIdx.x * 256 + tid;
    int v = (i < n) ? deg[i] : 0;
    if (i < n) dinv[i] = rsqrtf((float)(v + 1));  // +1 = self loop; always > 0
    s[tid] = v;
    __syncthreads();
    for (int off = 1; off < 256; off <<= 1) {
        int t = (tid >= off) ? s[tid - off] : 0;
        __syncthreads();
        s[tid] += t;
        __syncthreads();
    }
    if (i < n) partial[i] = s[tid] - v;  // exclusive within block
    if (tid == 255) bsum[blockIdx.x] = s[255];
}

// single block, 512 threads: exclusive scan of block sums (NB=391 <= 512)
__global__ void k_scan_bsum(const int* __restrict__ bsum, int* __restrict__ bsumex, int nb) {
    __shared__ int s[512];
    int tid = threadIdx.x;
    int v = (tid < nb) ? bsum[tid] : 0;
    s[tid] = v;
    __syncthreads();
    for (int off = 1; off < 512; off <<= 1) {
        int t = (tid >= off) ? s[tid - off] : 0;
        __syncthreads();
        s[tid] += t;
        __syncthreads();
    }
    bsumex[tid] = s[tid] - v;
}

// offs = scanned; cursor starts as a copy of offs (so k_fill needs no offs gather)
__global__ void k_add_base(const int* __restrict__ partial, const int* __restrict__ bsumex,
                           int* __restrict__ offs, int* __restrict__ cursor, int n) {
    int i = blockIdx.x * 256 + threadIdx.x;
    if (i < n) {
        int v = partial[i] + bsumex[i >> 8];
        offs[i] = v;
        cursor[i] = v;
    }
}

__global__ void k_fill(const int* __restrict__ src, const int* __restrict__ dst,
                       int* __restrict__ cursor, int* __restrict__ csr, int E) {
    int e = blockIdx.x * 256 + threadIdx.x;
    if (e < E) {
        int pos = atomicAdd(&cursor[dst[e]], 1);
        csr[pos] = src[e];
    }
}

// ---------------- per-layer kernels ----------------

// h' = (in @ W) * dinv[row]   (f32; no fp32 MFMA on CDNA4 -> vector ALU, LDS staging)
__global__ __launch_bounds__(256) void k_gemm(const float* __restrict__ in,
                                              const float* __restrict__ W,
                                              const float* __restrict__ dinv,
                                              float* __restrict__ out) {
    __shared__ float Ws[64 * 64];        // 16 KB
    __shared__ float xs[16 * 65];        // pad 65: conflict-free
    int tid = threadIdx.x;

    const float4* W4 = (const float4*)W;
    float4* Ws4 = (float4*)Ws;
#pragma unroll
    for (int j = 0; j < 4; j++) Ws4[tid + j * 256] = W4[tid + j * 256];

    {
        const float4* in4 = (const float4*)(in + (size_t)blockIdx.x * 16 * 64);
        float4 xv = in4[tid];
        int f = tid * 4;
        int r = f >> 6, c = f & 63;
        xs[r * 65 + c + 0] = xv.x;
        xs[r * 65 + c + 1] = xv.y;
        xs[r * 65 + c + 2] = xv.z;
        xs[r * 65 + c + 3] = xv.w;
    }
    __syncthreads();

    int cg = tid & 15, rl = tid >> 4;
    float4 acc = {0.f, 0.f, 0.f, 0.f};
#pragma unroll
    for (int k = 0; k < 64; k++) {
        float xv = xs[rl * 65 + k];
        float4 wv = ((const float4*)Ws)[k * 16 + cg];
        acc.x += xv * wv.x;
        acc.y += xv * wv.y;
        acc.z += xv * wv.z;
        acc.w += xv * wv.w;
    }
    float d = dinv[blockIdx.x * 16 + rl];
    acc.x *= d; acc.y *= d; acc.z *= d; acc.w *= d;
    float4* out4 = (float4*)(out + (size_t)blockIdx.x * 16 * 64);
    out4[rl * 16 + cg] = acc;
}

// out[i] = relu(dinv_i * (h'[i] + sum_j h'[j]) + b), h' pre-scaled by dinv.
// 16 lanes per node (float4 each), 16 nodes/block: per wave 4 nodes x 4-unroll
// = 16 outstanding 256B gathers. Masked parallel tail (no serial remainder).
__global__ __launch_bounds__(256) void k_gather(const float* __restrict__ h,
                                                const float* __restrict__ dinv,
                                                const int* __restrict__ csr,
                                                const int* __restrict__ offs,
                                                const int* __restrict__ deg,
                                                const float* __restrict__ bias,
                                                float* __restrict__ out, int n) {
    int t = threadIdx.x;
    int node = blockIdx.x * 16 + (t >> 4);
    int q = t & 15;                       // feature group: 4 floats
    if (node >= n) return;
    int start = offs[node];
    int cnt = deg[node];
    const float4* h4 = (const float4*)h;

    float4 a0 = h4[(size_t)node * 16 + q];   // self loop (dinv_i applied again below)
    float4 a1 = {0.f,0.f,0.f,0.f}, a2 = {0.f,0.f,0.f,0.f}, a3 = {0.f,0.f,0.f,0.f};

    int e = 0;
    int cnt4 = cnt & ~3;
    for (; e < cnt4; e += 4) {
        int j0 = csr[start + e + 0];
        int j1 = csr[start + e + 1];
        int j2 = csr[start + e + 2];
        int j3 = csr[start + e + 3];
        float4 v0 = h4[(size_t)j0 * 16 + q];
        float4 v1 = h4[(size_t)j1 * 16 + q];
        float4 v2 = h4[(size_t)j2 * 16 + q];
        float4 v3 = h4[(size_t)j3 * 16 + q];
        a0.x += v0.x; a0.y += v0.y; a0.z += v0.z; a0.w += v0.w;
        a1.x += v1.x; a1.y += v1.y; a1.z += v1.z; a1.w += v1.w;
        a2.x += v2.x; a2.y += v2.y; a2.z += v2.z; a2.w += v2.w;
        a3.x += v3.x; a3.y += v3.y; a3.z += v3.z; a3.w += v3.w;
    }
    int rem = cnt - e;                    // 0..3, one masked parallel iteration
    if (rem > 0) {
        int j0 = csr[start + e];
        int j1 = (rem > 1) ? csr[start + e + 1] : j0;
        int j2 = (rem > 2) ? csr[start + e + 2] : j0;
        float4 v0 = h4[(size_t)j0 * 16 + q];
        float4 v1 = h4[(size_t)j1 * 16 + q];
        float4 v2 = h4[(size_t)j2 * 16 + q];
        a0.x += v0.x; a0.y += v0.y; a0.z += v0.z; a0.w += v0.w;
        if (rem > 1) { a1.x += v1.x; a1.y += v1.y; a1.z += v1.z; a1.w += v1.w; }
        if (rem > 2) { a2.x += v2.x; a2.y += v2.y; a2.z += v2.z; a2.w += v2.w; }
    }

    float4 a;
    a.x = (a0.x + a1.x) + (a2.x + a3.x);
    a.y = (a0.y + a1.y) + (a2.y + a3.y);
    a.z = (a0.z + a1.z) + (a2.z + a3.z);
    a.w = (a0.w + a1.w) + (a2.w + a3.w);
    float d = dinv[node];
    float4 b = ((const float4*)bias)[q];
    float4 r;
    r.x = fmaxf(fmaf(a.x, d, b.x), 0.f);
    r.y = fmaxf(fmaf(a.y, d, b.y), 0.f);
    r.z = fmaxf(fmaf(a.z, d, b.z), 0.f);
    r.w = fmaxf(fmaf(a.w, d, b.w), 0.f);
    ((float4*)out)[(size_t)node * 16 + q] = r;
}

// ---------------- launch ----------------

extern "C" void kernel_launch(void* const* d_in, const int* in_sizes, int n_in,
                              void* d_out, int out_size, void* d_ws, size_t ws_size,
                              hipStream_t stream) {
    const float* x  = (const float*)d_in[0];
    const int*   ei = (const int*)d_in[1];
    const float* W0 = (const float*)d_in[2];
    const float* b0 = (const float*)d_in[3];
    const float* W1 = (const float*)d_in[4];
    const float* b1 = (const float*)d_in[5];
    const float* W2 = (const float*)d_in[6];
    const float* b2 = (const float*)d_in[7];
    float* out = (float*)d_out;

    const int N = N_NODES;
    const int E = in_sizes[1] / 2;
    const int* src = ei;
    const int* dst = ei + E;

    char* p = (char*)d_ws;
    auto alloc = [&](size_t bytes) -> void* {
        void* r = (void*)p;
        p += (bytes + 511) & ~(size_t)511;
        return r;
    };
    int*   deg     = (int*)alloc((size_t)N * 4);
    int*   cursor  = (int*)alloc((size_t)N * 4);
    float* dinv    = (float*)alloc((size_t)N * 4);
    int*   partial = (int*)alloc((size_t)N * 4);
    int*   offs    = (int*)alloc((size_t)N * 4);
    int*   bsum    = (int*)alloc(512 * 4);
    int*   bsumex  = (int*)alloc(512 * 4);
    int*   csr     = (int*)alloc((size_t)E * 4 + 1024);
    float* bufA    = (float*)alloc((size_t)N * DFEAT * 4);
    float* bufB    = (float*)alloc((size_t)N * DFEAT * 4);

    const int NB = (N + 255) / 256;      // 391
    const int EB = (E + 255) / 256;      // 3907
    const int GEMM_B = N / 16;           // 6250
    const int GATH_B = (N + 15) / 16;    // 6250

    // CSR build (amortized over 3 layers)
    k_init<<<NB, 256, 0, stream>>>(deg, N);
    k_count<<<EB, 256, 0, stream>>>(dst, deg, E);
    k_scan_local<<<NB, 256, 0, stream>>>(deg, partial, bsum, dinv, N);
    k_scan_bsum<<<1, 512, 0, stream>>>(bsum, bsumex, NB);
    k_add_base<<<NB, 256, 0, stream>>>(partial, bsumex, offs, cursor, N);
    k_fill<<<EB, 256, 0, stream>>>(src, dst, cursor, csr, E);

    // layer 0: x -> A -> B
    k_gemm<<<GEMM_B, 256, 0, stream>>>(x, W0, dinv, bufA);
    k_gather<<<GATH_B, 256, 0, stream>>>(bufA, dinv, csr, offs, deg, b0, bufB, N);
    // layer 1: B -> A -> B
    k_gemm<<<GEMM_B, 256, 0, stream>>>(bufB, W1, dinv, bufA);
    k_gather<<<GATH_B, 256, 0, stream>>>(bufA, dinv, csr, offs, deg, b1, bufB, N);
    // layer 2: B -> A -> out
    k_gemm<<<GEMM_B, 256, 0, stream>>>(bufB, W2, dinv, bufA);
    k_gather<<<GATH_B, 256, 0, stream>>>(bufA, dinv, csr, offs, deg, b2, out, N);
}